// Round 7
// baseline (68.810 us; speedup 1.0000x reference)
//
#include <hip/hip_runtime.h>
#include <hip/hip_bf16.h>

typedef _Float16 half_t;
typedef _Float16 f16x8 __attribute__((ext_vector_type(8)));
typedef _Float16 f16x4 __attribute__((ext_vector_type(4)));
typedef float f32x4 __attribute__((ext_vector_type(4)));

#define LEAKY 0.1f

// ===========================================================================
// prep: wp234 = [layer(3)][tap(10)][co(48)][ci(48)], tap 9 = zeros (69120 h)
// ===========================================================================
__global__ __launch_bounds__(512) void prep_w_k(const float* __restrict__ w2,
                                                const float* __restrict__ w3,
                                                const float* __restrict__ w4,
                                                half_t* __restrict__ wp234)
{
    int t = blockIdx.x * 512 + threadIdx.x;
    if (t >= 3 * 23040) return;
    int layer = t / 23040;
    int r = t % 23040;
    int tap = r / 2304;
    int r2 = r % 2304;
    int co = r2 / 48, ci = r2 % 48;
    const float* src = layer == 0 ? w2 : (layer == 1 ? w3 : w4);
    float v = 0.f;
    if (tap < 9) v = src[((co * 48 + ci) * 3 + tap / 3) * 3 + tap % 3];
    wp234[t] = (half_t)v;
}

// ===========================================================================
// Fused conv1(3->48) + conv2(48->48) + bias/leaky + 2x2 maxpool.
// Block: 256 thr = 4 waves; conv2-input tile 8 rows x 32 cols -> pooled 4x16.
// conv1 computes the 10x34 halo tile directly into LDS in_t[px][56] via
// swapped-operand MFMA (a=weights, b=pixels) -> ds_write_b64 in conv2's
// native A layout. conv2: K = tap*48+ci (432 pad 448, 14 steps), B from L2.
// LDS = 46 KB -> 3 blocks/CU; grid 2048 blocks for deep pipelining.
// ===========================================================================
__global__ __launch_bounds__(256, 3) void conv12_k(const float* __restrict__ x,
                                                   const float* __restrict__ w1,
                                                   const float* __restrict__ b1,
                                                   const half_t* __restrict__ wp2,
                                                   const float* __restrict__ b2,
                                                   half_t* __restrict__ out)
{
    __shared__ alignas(16) half_t in_t[352 * 56];   // conv1 out [px=row*34+col][co56]
    __shared__ alignas(16) half_t xt[13][36][4];    // x patch, ci-minor (pad 4)
    __shared__ alignas(16) half_t w1t[48 * 40];     // [co][k40], 27..39 = 0

    const int tid = threadIdx.x;
    const int n = blockIdx.z;
    const int hblk = blockIdx.x * 8, wblk = blockIdx.y * 32;
    const int lane = tid & 63, hp = tid >> 6;       // 4 waves = h-pairs 0..3
    const int m = lane & 15, g = lane >> 4;

    // ---- stage w1 transform: [co][40], k = tap*3+ci ----
    for (int t = tid; t < 1920; t += 256) {
        int co = t / 40, kk = t % 40;
        float v = 0.f;
        if (kk < 27) {
            int tap = kk / 3, ci = kk % 3;
            v = w1[((co * 3 + ci) * 3 + tap / 3) * 3 + tap % 3];
        }
        w1t[t] = (half_t)v;
    }
    // ---- stage x patch rows hblk-2..hblk+10 (13), cols wblk-2..wblk+33 (36) ----
    for (int c = tid; c < 1404; c += 256) {
        int ci = c / 468, rem = c % 468;
        int row = rem / 36, col = rem % 36;
        int gh = hblk - 2 + row, gw = wblk - 2 + col;
        float v = 0.f;
        if ((unsigned)gh < 256u && (unsigned)gw < 256u)
            v = x[((n * 3 + ci) * 256 + gh) * 256 + gw];
        xt[row][col][ci] = (half_t)v;
    }
    __syncthreads();

    // =================== conv1 phase ===================
    int xoff[8];
    #pragma unroll
    for (int j = 0; j < 8; ++j) {
        int k = g * 8 + j;
        int tap = k / 3, ci = k - 3 * tap;
        int dr = tap / 3, ds = tap - 3 * dr;
        xoff[j] = (k < 27) ? ((dr * 36 + ds) * 8 + ci * 2) : 0;   // k>=27: weight=0
    }
    f16x8 wf[3];
    float bb1[12];
    #pragma unroll
    for (int nt = 0; nt < 3; ++nt) {
        wf[nt] = *(const f16x8*)((const char*)w1t + (nt * 16 + m) * 80 + g * 16);
        #pragma unroll
        for (int j = 0; j < 4; ++j) bb1[nt * 4 + j] = b1[nt * 16 + 4 * g + j];
    }
    const char* xtb = (const char*)&xt[0][0][0];
    // 22 pixel-tiles of 16 cover px 0..351 (340..351 = slop, never read)
    #pragma unroll
    for (int tt = 0; tt < 6; ++tt) {
        int t = hp + tt * 4;
        if (t < 22) {
            int px = t * 16 + m;
            int row = px / 34, col = px - row * 34;
            int pxb = (row * 36 + col) * 8;
            f16x8 pf;
            #pragma unroll
            for (int j = 0; j < 8; ++j)
                pf[j] = *(const half_t*)(xtb + pxb + xoff[j]);
            bool inb = ((unsigned)(hblk - 1 + row) < 256u) && ((unsigned)(wblk - 1 + col) < 256u);
            #pragma unroll
            for (int nt = 0; nt < 3; ++nt) {
                f32x4 d = {0.f, 0.f, 0.f, 0.f};
                d = __builtin_amdgcn_mfma_f32_16x16x32_f16(wf[nt], pf, d, 0, 0, 0);
                f16x4 o;
                #pragma unroll
                for (int j = 0; j < 4; ++j) {
                    float v = d[j] + bb1[nt * 4 + j];
                    v = v > 0.f ? v : LEAKY * v;
                    o[j] = inb ? (half_t)v : (half_t)0.f;
                }
                *(f16x4*)(&in_t[px * 56 + nt * 16 + 4 * g]) = o;
            }
        }
    }
    __syncthreads();

    // =================== conv2 phase ===================
    const int hpar = m & 1, wloc = m >> 1;
    const int abase = hp * 2 * 34 * 112;
    const char* ib = (const char*)&in_t[0];
    const char* bp = (const char*)wp2 + m * 96;

    f32x4 acc[4][3];
    #pragma unroll
    for (int mt = 0; mt < 4; ++mt)
        #pragma unroll
        for (int nt = 0; nt < 3; ++nt)
            acc[mt][nt] = (f32x4){0.f, 0.f, 0.f, 0.f};

    #pragma unroll
    for (int s = 0; s < 14; ++s) {
        int kc = 4 * s + g;
        int tap = kc / 6, ci8 = kc - tap * 6;
        int dr = tap / 3, ds = tap - 3 * dr;
        if (tap == 9) { dr = 0; ds = 0; }
        int aoff = ((hpar + dr) * 34 + (wloc + ds)) * 112 + ci8 * 16;
        int boff = tap * 4608 + ci8 * 16;
        f16x8 b0 = *(const f16x8*)(bp + boff);
        f16x8 b1f = *(const f16x8*)(bp + boff + 1536);
        f16x8 b2f = *(const f16x8*)(bp + boff + 3072);
        f16x8 a[4];
        #pragma unroll
        for (int mt = 0; mt < 4; ++mt)
            a[mt] = *(const f16x8*)(ib + abase + aoff + mt * 896);
        __builtin_amdgcn_s_setprio(1);
        #pragma unroll
        for (int mt = 0; mt < 4; ++mt) {
            acc[mt][0] = __builtin_amdgcn_mfma_f32_16x16x32_f16(a[mt], b0, acc[mt][0], 0, 0, 0);
            acc[mt][1] = __builtin_amdgcn_mfma_f32_16x16x32_f16(a[mt], b1f, acc[mt][1], 0, 0, 0);
            acc[mt][2] = __builtin_amdgcn_mfma_f32_16x16x32_f16(a[mt], b2f, acc[mt][2], 0, 0, 0);
        }
        __builtin_amdgcn_s_setprio(0);
    }

    // ---- epilogue: bias + leaky + 2x2 maxpool -> act2 NHWC-48 ----
    int hq = blockIdx.x * 4 + hp;
    #pragma unroll
    for (int nt = 0; nt < 3; ++nt) {
        int co = nt * 16 + m;
        float bb = b2[co];
        #pragma unroll
        for (int mt = 0; mt < 4; ++mt) {
            float pmax = -1e30f;
            #pragma unroll
            for (int j = 0; j < 4; ++j) {
                float v = acc[mt][nt][j] + bb;
                v = v > 0.f ? v : LEAKY * v;
                pmax = fmaxf(pmax, v);
            }
            int wq = blockIdx.y * 16 + mt * 4 + g;
            out[((n * 128 + hq) * 128 + wq) * 48 + co] = (half_t)pmax;
        }
    }
}

// ===========================================================================
// convpool (48->48, 3x3 pad1 + bias + leaky + 2x2 maxpool), single-phase K.
// Block: 256 thr = 4 waves; wave = 1 h-pair x (8*MT) cols. A: LDS; B: global.
// NTS = couts computed per block / 16 (grid z = ntb*8 + n for NTS<3).
// ===========================================================================
template<int H, int W, int MT, int NTS, bool FINAL>
__global__ __launch_bounds__(256, 4)
void convpool4_k(const half_t* __restrict__ in,
                 const half_t* __restrict__ wp,
                 const float* __restrict__ bias,
                 void* __restrict__ outv)
{
    constexpr int HO = H / 2, WO = W / 2;
    constexpr int TC = 8 * MT + 2;
    constexpr int NU4 = 10 * TC * 6;

    __shared__ alignas(16) half_t in_t[10][TC][56];

    int tid = threadIdx.x;
    int n = blockIdx.z & 7, ntb = blockIdx.z >> 3;
    int hblk = blockIdx.x * 8, wblk = blockIdx.y * (8 * MT);
    int lane = tid & 63, hp = tid >> 6;
    int m = lane & 15, g = lane >> 4;
    int hpar = m & 1, wloc = m >> 1;

    {
        const uint4* s4 = (const uint4*)in;
        uint4* d = (uint4*)&in_t[0][0][0];
        #pragma unroll
        for (int i = 0; i < (NU4 + 255) / 256; ++i) {
            int c = tid + i * 256;
            if (c < NU4) {
                int row = c / (TC * 6);
                int rem = c - row * (TC * 6);
                int pix = rem / 6;
                int sub = rem - pix * 6;
                int gh = hblk - 1 + row, gw = wblk - 1 + pix;
                uint4 v = {0u, 0u, 0u, 0u};
                if ((unsigned)gh < (unsigned)H && (unsigned)gw < (unsigned)W)
                    v = s4[((n * H + gh) * W + gw) * 6 + sub];
                d[(row * TC + pix) * 7 + sub] = v;
            }
        }
    }

    int abase = hp * 2 * TC * 112;
    const char* ib = (const char*)&in_t[0][0][0];
    const char* bp = (const char*)wp + m * 96 + ntb * NTS * 1536;

    f32x4 acc[MT][NTS];
    #pragma unroll
    for (int mt = 0; mt < MT; ++mt)
        #pragma unroll
        for (int nt = 0; nt < NTS; ++nt)
            acc[mt][nt] = (f32x4){0.f, 0.f, 0.f, 0.f};

    __syncthreads();

    #pragma unroll
    for (int s = 0; s < 14; ++s) {
        int kc = 4 * s + g;
        int tap = kc / 6, ci8 = kc - tap * 6;
        int dr = tap / 3, ds = tap - 3 * dr;
        if (tap == 9) { dr = 0; ds = 0; }
        int aoff = ((hpar + dr) * TC + (wloc + ds)) * 112 + ci8 * 16;
        int boff = tap * 4608 + ci8 * 16;
        f16x8 bfrag[NTS];
        #pragma unroll
        for (int nt = 0; nt < NTS; ++nt)
            bfrag[nt] = *(const f16x8*)(bp + boff + nt * 1536);
        f16x8 a[MT];
        #pragma unroll
        for (int mt = 0; mt < MT; ++mt)
            a[mt] = *(const f16x8*)(ib + abase + aoff + mt * 896);
        __builtin_amdgcn_s_setprio(1);
        #pragma unroll
        for (int mt = 0; mt < MT; ++mt)
            #pragma unroll
            for (int nt = 0; nt < NTS; ++nt)
                acc[mt][nt] = __builtin_amdgcn_mfma_f32_16x16x32_f16(a[mt], bfrag[nt], acc[mt][nt], 0, 0, 0);
        __builtin_amdgcn_s_setprio(0);
    }

    int hq = blockIdx.x * 4 + hp;
    #pragma unroll
    for (int nt = 0; nt < NTS; ++nt) {
        int co = (ntb * NTS + nt) * 16 + m;
        float bb = bias[co];
        #pragma unroll
        for (int mt = 0; mt < MT; ++mt) {
            float pmax = -1e30f;
            #pragma unroll
            for (int j = 0; j < 4; ++j) {
                float v = acc[mt][nt][j] + bb;
                v = v > 0.f ? v : LEAKY * v;
                pmax = fmaxf(pmax, v);
            }
            int wq = blockIdx.y * (4 * MT) + mt * 4 + g;
            if (FINAL)
                ((float*)outv)[(((long)n * 48 + co) * HO + hq) * WO + wq] = pmax;
            else
                ((half_t*)outv)[((n * HO + hq) * WO + wq) * 48 + co] = (half_t)pmax;
        }
    }
}

// ===========================================================================
extern "C" void kernel_launch(void* const* d_in, const int* in_sizes, int n_in,
                              void* d_out, int out_size, void* d_ws, size_t ws_size,
                              hipStream_t stream)
{
    const float* x  = (const float*)d_in[0];
    const float* w1 = (const float*)d_in[1];
    const float* b1 = (const float*)d_in[2];
    const float* w2 = (const float*)d_in[3];
    const float* b2 = (const float*)d_in[4];
    const float* w3 = (const float*)d_in[5];
    const float* b3 = (const float*)d_in[6];
    const float* w4 = (const float*)d_in[7];
    const float* b4 = (const float*)d_in[8];

    half_t* Wb = (half_t*)d_ws;
    half_t* wp2  = Wb;                      // [3][10][48][48] = 69120 halfs
    half_t* wp3  = wp2 + 23040;
    half_t* wp4  = wp3 + 23040;
    half_t* act2 = Wb + 69120;              // 8*128*128*48 = 6291456
    half_t* act3 = act2 + 6291456;          // 8*64*64*48   = 1572864

    prep_w_k<<<dim3(135), 512, 0, stream>>>(w2, w3, w4, wp2);

    // fused conv1+conv2: 3->48->48 @256 + pool -> act2 (128x128 NHWC-48)
    conv12_k<<<dim3(32, 8, 8), 256, 0, stream>>>(x, w1, b1, wp2, b2, act2);
    // conv3: 48->48 @128 + pool -> 64
    convpool4_k<128, 128, 4, 3, false><<<dim3(16, 4, 8), 256, 0, stream>>>(act2, wp3, b3, act3);
    // conv4: 48->48 @64 + pool -> 32, fp32 NCHW out; cout split 3-ways
    convpool4_k<64, 64, 2, 1, true><<<dim3(8, 4, 24), 256, 0, stream>>>(act3, wp4, b4, d_out);
}

// Round 8
// 57.743 us; speedup vs baseline: 1.1917x; 1.1917x over previous
//
#include <hip/hip_runtime.h>
#include <hip/hip_bf16.h>

typedef _Float16 half_t;
typedef _Float16 f16x8 __attribute__((ext_vector_type(8)));
typedef _Float16 f16x4 __attribute__((ext_vector_type(4)));
typedef float f32x4 __attribute__((ext_vector_type(4)));

#define LEAKY 0.1f

// ===========================================================================
// prep: wp1 = [co(48)][40] (k = tap*3+ci, 27..39 = 0)
//       wp2 = [tap(10)][ci8(6)][m(16)][nt(3)][j(8)] halfs, tap 9 = zeros.
//       Element (tap,ci8,m,nt,j) = w2[co=nt*16+m][ci=ci8*8+j][tap].
// ===========================================================================
__global__ __launch_bounds__(512) void prep_w_k(const float* __restrict__ w1,
                                                const float* __restrict__ w2,
                                                half_t* __restrict__ wp1,
                                                half_t* __restrict__ wp2)
{
    int t = blockIdx.x * 512 + threadIdx.x;
    if (t < 1920) {
        int co = t / 40, kk = t % 40;
        float v = 0.f;
        if (kk < 27) {
            int tap = kk / 3, ci = kk % 3;
            v = w1[((co * 3 + ci) * 3 + tap / 3) * 3 + tap % 3];
        }
        wp1[t] = (half_t)v;
        return;
    }
    int t2 = t - 1920;
    if (t2 >= 23040) return;
    int tap = t2 / 2304, r = t2 % 2304;
    int ci8 = r / 384, r2 = r % 384;
    int mm = r2 / 24, r3 = r2 % 24;
    int nt = r3 / 8, j = r3 % 8;
    int co = nt * 16 + mm, ci = ci8 * 8 + j;
    float v = 0.f;
    if (tap < 9) v = w2[((co * 48 + ci) * 3 + tap / 3) * 3 + tap % 3];
    wp2[t2] = (half_t)v;
}

// ===========================================================================
// Fused conv1(3->48) + conv2(48->48) + bias/leaky + 2x2 maxpool.
// Block: 512 thr = 8 waves; conv2-input tile 16 rows x 32 cols -> pooled 8x16.
// conv1: swapped-operand MFMA (a=weights, b=pixels) -> ds_write_b64 directly
// into conv2's A layout in_t[px][56]. conv2: K=(tap,ci) 432 pad 448, 14 steps;
// B from global (re-packed layout, 48 B/lane contiguous), 1-deep B ping-pong.
// Blocks 0..89 also emit the wp34 global weight transform for conv3/conv4.
// ===========================================================================
__global__ __launch_bounds__(512, 4) void conv12_k(const float* __restrict__ x,
                                                   const half_t* __restrict__ wp1,
                                                   const float* __restrict__ b1,
                                                   const half_t* __restrict__ wp2,
                                                   const float* __restrict__ b2,
                                                   const float* __restrict__ w3,
                                                   const float* __restrict__ w4,
                                                   half_t* __restrict__ wp34,
                                                   half_t* __restrict__ out)
{
    __shared__ alignas(16) half_t in_t[624 * 56];   // conv1 out [px=row*34+col][co56]
    __shared__ alignas(16) half_t xt[21][36][4];    // x patch, ci-minor (pad 4)
    __shared__ alignas(16) half_t w1t[1920];        // [co][40]

    const int tid = threadIdx.x;
    const int n = blockIdx.z;
    const int hblk = blockIdx.x * 16, wblk = blockIdx.y * 32;
    const int lane = tid & 63, hp = tid >> 6;       // 8 waves = h-pairs 0..7
    const int m = lane & 15, g = lane >> 4;

    // ---- folded wp3/wp4 prep (blocks 0..89, one elem/thread) ----
    {
        int bid = blockIdx.x + 16 * (blockIdx.y + 8 * blockIdx.z);
        int t2 = bid * 512 + tid;
        if (t2 < 46080) {
            int layer = t2 / 23040, r0 = t2 % 23040;
            int tap = r0 / 2304, r = r0 % 2304;
            int ci8 = r / 384, r2 = r % 384;
            int mm = r2 / 24, r3 = r2 % 24;
            int nt = r3 / 8, j = r3 % 8;
            int co = nt * 16 + mm, ci = ci8 * 8 + j;
            const float* src = layer ? w4 : w3;
            float v = 0.f;
            if (tap < 9) v = src[((co * 48 + ci) * 3 + tap / 3) * 3 + tap % 3];
            wp34[t2] = (half_t)v;
        }
    }
    // ---- w1t: linear copy 240 uint4 ----
    {
        const uint4* s = (const uint4*)wp1;
        uint4* d = (uint4*)w1t;
        if (tid < 240) d[tid] = s[tid];
    }
    // ---- xt: rows hblk-2..hblk+18 (21), cols wblk-2..wblk+33 (36) ----
    for (int c = tid; c < 2268; c += 512) {
        int ci = c / 756, rem = c % 756;
        int row = rem / 36, col = rem % 36;
        int gh = hblk - 2 + row, gw = wblk - 2 + col;
        float v = 0.f;
        if ((unsigned)gh < 256u && (unsigned)gw < 256u)
            v = x[((n * 3 + ci) * 256 + gh) * 256 + gw];
        xt[row][col][ci] = (half_t)v;
    }
    __syncthreads();

    // =================== conv1 phase ===================
    int xoff[8];
    #pragma unroll
    for (int j = 0; j < 8; ++j) {
        int k = g * 8 + j;
        int tap = k / 3, ci = k - 3 * tap;
        int dr = tap / 3, ds = tap - 3 * dr;
        xoff[j] = (k < 27) ? ((dr * 36 + ds) * 8 + ci * 2) : 0;   // k>=27: weight=0
    }
    f16x8 wf[3];
    float bb1[12];
    #pragma unroll
    for (int nt = 0; nt < 3; ++nt) {
        wf[nt] = *(const f16x8*)((const char*)w1t + (nt * 16 + m) * 80 + g * 16);
        float4 bv = *(const float4*)(b1 + nt * 16 + 4 * g);
        bb1[nt * 4 + 0] = bv.x; bb1[nt * 4 + 1] = bv.y;
        bb1[nt * 4 + 2] = bv.z; bb1[nt * 4 + 3] = bv.w;
    }
    const char* xtb = (const char*)&xt[0][0][0];
    // 39 pixel-tiles of 16 cover px 0..623 (612..623 slop, never read)
    for (int t = hp; t < 39; t += 8) {
        int px = t * 16 + m;
        int row = px / 34, col = px - row * 34;
        int pxb = (row * 36 + col) * 8;
        f16x8 pf;
        #pragma unroll
        for (int j = 0; j < 8; ++j)
            pf[j] = *(const half_t*)(xtb + pxb + xoff[j]);
        bool inb = ((unsigned)(hblk - 1 + row) < 256u) && ((unsigned)(wblk - 1 + col) < 256u);
        #pragma unroll
        for (int nt = 0; nt < 3; ++nt) {
            f32x4 d = {0.f, 0.f, 0.f, 0.f};
            d = __builtin_amdgcn_mfma_f32_16x16x32_f16(wf[nt], pf, d, 0, 0, 0);
            f16x4 o;
            #pragma unroll
            for (int j = 0; j < 4; ++j) {
                float v = d[j] + bb1[nt * 4 + j];
                v = v > 0.f ? v : LEAKY * v;
                o[j] = inb ? (half_t)v : (half_t)0.f;
            }
            *(f16x4*)(&in_t[px * 56 + nt * 16 + 4 * g]) = o;
        }
    }
    __syncthreads();

    // =================== conv2 phase ===================
    const int hpar = m & 1, wloc = m >> 1;
    const int abase = hp * 7616;                    // 2*hp * 34 * 112
    const char* ib = (const char*)in_t;
    const char* bp = (const char*)wp2 + m * 48;

    f32x4 acc[4][3];
    #pragma unroll
    for (int mt = 0; mt < 4; ++mt)
        #pragma unroll
        for (int nt = 0; nt < 3; ++nt)
            acc[mt][nt] = (f32x4){0.f, 0.f, 0.f, 0.f};

    f16x8 bf[2][3], af[4];

#define BLOAD(S, P) { \
    int kc = 4 * (S) + g; int tap = kc / 6, ci8 = kc - tap * 6; \
    int boff = tap * 4608 + ci8 * 768; \
    bf[P][0] = *(const f16x8*)(bp + boff); \
    bf[P][1] = *(const f16x8*)(bp + boff + 16); \
    bf[P][2] = *(const f16x8*)(bp + boff + 32); }
#define ALOAD(S) { \
    int kc = 4 * (S) + g; int tap = kc / 6, ci8 = kc - tap * 6; \
    int dr = tap / 3, ds = tap - 3 * dr; \
    if (tap == 9) { dr = 0; ds = 0; } \
    int aoff = ((hpar + dr) * 34 + (wloc + ds)) * 112 + ci8 * 16 + abase; \
    af[0] = *(const f16x8*)(ib + aoff); \
    af[1] = *(const f16x8*)(ib + aoff + 896); \
    af[2] = *(const f16x8*)(ib + aoff + 1792); \
    af[3] = *(const f16x8*)(ib + aoff + 2688); }
#define MM(P) { \
    __builtin_amdgcn_s_setprio(1); \
    _Pragma("unroll") \
    for (int mt = 0; mt < 4; ++mt) { \
        acc[mt][0] = __builtin_amdgcn_mfma_f32_16x16x32_f16(af[mt], bf[P][0], acc[mt][0], 0, 0, 0); \
        acc[mt][1] = __builtin_amdgcn_mfma_f32_16x16x32_f16(af[mt], bf[P][1], acc[mt][1], 0, 0, 0); \
        acc[mt][2] = __builtin_amdgcn_mfma_f32_16x16x32_f16(af[mt], bf[P][2], acc[mt][2], 0, 0, 0); \
    } \
    __builtin_amdgcn_s_setprio(0); }

    BLOAD(0, 0);
    #pragma unroll
    for (int ss = 0; ss < 7; ++ss) {
        BLOAD(2 * ss + 1, 1);
        ALOAD(2 * ss);
        MM(0);
        if (ss < 6) BLOAD(2 * ss + 2, 0);
        ALOAD(2 * ss + 1);
        MM(1);
    }
#undef BLOAD
#undef ALOAD
#undef MM

    // ---- epilogue: bias + leaky + 2x2 maxpool -> act2 NHWC-48 ----
    int hq = blockIdx.x * 8 + hp;
    #pragma unroll
    for (int nt = 0; nt < 3; ++nt) {
        int co = nt * 16 + m;
        float bb = b2[co];
        #pragma unroll
        for (int mt = 0; mt < 4; ++mt) {
            float pmax = -1e30f;
            #pragma unroll
            for (int j = 0; j < 4; ++j) {
                float v = acc[mt][nt][j] + bb;
                v = v > 0.f ? v : LEAKY * v;
                pmax = fmaxf(pmax, v);
            }
            int wq = blockIdx.y * 16 + mt * 4 + g;
            out[((n * 128 + hq) * 128 + wq) * 48 + co] = (half_t)pmax;
        }
    }
}

// ===========================================================================
// convpool (48->48, 3x3 pad1 + bias + leaky + 2x2 maxpool), single-phase K.
// Block: 256 thr = 4 waves; wave = 1 h-pair x (8*MT) cols. A: LDS; B: global
// (re-packed layout). NTS = couts/16 per block; grid z = ntb*8 + n.
// ===========================================================================
template<int H, int W, int MT, int NTS, bool FINAL>
__global__ __launch_bounds__(256, 4)
void convpool4_k(const half_t* __restrict__ in,
                 const half_t* __restrict__ wp,
                 const float* __restrict__ bias,
                 void* __restrict__ outv)
{
    constexpr int HO = H / 2, WO = W / 2;
    constexpr int TC = 8 * MT + 2;
    constexpr int NU4 = 10 * TC * 6;

    __shared__ alignas(16) half_t in_t[10][TC][56];

    int tid = threadIdx.x;
    int n = blockIdx.z & 7, ntb = blockIdx.z >> 3;
    int hblk = blockIdx.x * 8, wblk = blockIdx.y * (8 * MT);
    int lane = tid & 63, hp = tid >> 6;
    int m = lane & 15, g = lane >> 4;
    int hpar = m & 1, wloc = m >> 1;

    {
        const uint4* s4 = (const uint4*)in;
        uint4* d = (uint4*)&in_t[0][0][0];
        #pragma unroll
        for (int i = 0; i < (NU4 + 255) / 256; ++i) {
            int c = tid + i * 256;
            if (c < NU4) {
                int row = c / (TC * 6);
                int rem = c - row * (TC * 6);
                int pix = rem / 6;
                int sub = rem - pix * 6;
                int gh = hblk - 1 + row, gw = wblk - 1 + pix;
                uint4 v = {0u, 0u, 0u, 0u};
                if ((unsigned)gh < (unsigned)H && (unsigned)gw < (unsigned)W)
                    v = s4[((n * H + gh) * W + gw) * 6 + sub];
                d[(row * TC + pix) * 7 + sub] = v;
            }
        }
    }

    int abase = hp * 2 * TC * 112;
    const char* ib = (const char*)&in_t[0][0][0];
    const char* bp = (const char*)wp + m * 48;

    f32x4 acc[MT][NTS];
    #pragma unroll
    for (int mt = 0; mt < MT; ++mt)
        #pragma unroll
        for (int nt = 0; nt < NTS; ++nt)
            acc[mt][nt] = (f32x4){0.f, 0.f, 0.f, 0.f};

    __syncthreads();

    #pragma unroll
    for (int s = 0; s < 14; ++s) {
        int kc = 4 * s + g;
        int tap = kc / 6, ci8 = kc - tap * 6;
        int dr = tap / 3, ds = tap - 3 * dr;
        if (tap == 9) { dr = 0; ds = 0; }
        int aoff = ((hpar + dr) * TC + (wloc + ds)) * 112 + ci8 * 16;
        int boff = tap * 4608 + ci8 * 768;
        f16x8 bfrag[NTS];
        #pragma unroll
        for (int nt = 0; nt < NTS; ++nt)
            bfrag[nt] = *(const f16x8*)(bp + boff + (ntb * NTS + nt) * 16);
        f16x8 a[MT];
        #pragma unroll
        for (int mt = 0; mt < MT; ++mt)
            a[mt] = *(const f16x8*)(ib + abase + aoff + mt * 896);
        __builtin_amdgcn_s_setprio(1);
        #pragma unroll
        for (int mt = 0; mt < MT; ++mt)
            #pragma unroll
            for (int nt = 0; nt < NTS; ++nt)
                acc[mt][nt] = __builtin_amdgcn_mfma_f32_16x16x32_f16(a[mt], bfrag[nt], acc[mt][nt], 0, 0, 0);
        __builtin_amdgcn_s_setprio(0);
    }

    int hq = blockIdx.x * 4 + hp;
    #pragma unroll
    for (int nt = 0; nt < NTS; ++nt) {
        int co = (ntb * NTS + nt) * 16 + m;
        float bb = bias[co];
        #pragma unroll
        for (int mt = 0; mt < MT; ++mt) {
            float pmax = -1e30f;
            #pragma unroll
            for (int j = 0; j < 4; ++j) {
                float v = acc[mt][nt][j] + bb;
                v = v > 0.f ? v : LEAKY * v;
                pmax = fmaxf(pmax, v);
            }
            int wq = blockIdx.y * (4 * MT) + mt * 4 + g;
            if (FINAL)
                ((float*)outv)[(((long)n * 48 + co) * HO + hq) * WO + wq] = pmax;
            else
                ((half_t*)outv)[((n * HO + hq) * WO + wq) * 48 + co] = (half_t)pmax;
        }
    }
}

// ===========================================================================
extern "C" void kernel_launch(void* const* d_in, const int* in_sizes, int n_in,
                              void* d_out, int out_size, void* d_ws, size_t ws_size,
                              hipStream_t stream)
{
    const float* x  = (const float*)d_in[0];
    const float* w1 = (const float*)d_in[1];
    const float* b1 = (const float*)d_in[2];
    const float* w2 = (const float*)d_in[3];
    const float* b2 = (const float*)d_in[4];
    const float* w3 = (const float*)d_in[5];
    const float* b3 = (const float*)d_in[6];
    const float* w4 = (const float*)d_in[7];
    const float* b4 = (const float*)d_in[8];

    half_t* Wb = (half_t*)d_ws;
    half_t* wp1  = Wb;                      // 1920 (pad 2048)
    half_t* wp2  = Wb + 2048;               // 23040
    half_t* wp34 = wp2 + 23040;             // 2 x 23040
    half_t* act2 = wp34 + 46080;            // 8*128*128*48 = 6291456
    half_t* act3 = act2 + 6291456;          // 8*64*64*48   = 1572864

    prep_w_k<<<dim3(49), 512, 0, stream>>>(w1, w2, wp1, wp2);

    // fused conv1+conv2: 3->48->48 @256 + pool -> act2 (128x128 NHWC-48)
    conv12_k<<<dim3(16, 8, 8), 512, 0, stream>>>(x, wp1, b1, wp2, b2, w3, w4, wp34, act2);
    // conv3: 48->48 @128 + pool -> 64
    convpool4_k<128, 128, 4, 3, false><<<dim3(16, 4, 8), 256, 0, stream>>>(act2, wp34, b3, act3);
    // conv4: 48->48 @64 + pool -> 32, fp32 NCHW out; cout split 3-ways
    convpool4_k<64, 64, 2, 1, true><<<dim3(8, 4, 24), 256, 0, stream>>>(act3, wp34 + 23040, b4, d_out);
}

// Round 9
// 57.727 us; speedup vs baseline: 1.1920x; 1.0003x over previous
//
#include <hip/hip_runtime.h>
#include <hip/hip_bf16.h>

typedef _Float16 half_t;
typedef _Float16 f16x8 __attribute__((ext_vector_type(8)));
typedef _Float16 f16x4 __attribute__((ext_vector_type(4)));
typedef float f32x4 __attribute__((ext_vector_type(4)));

#define LEAKY 0.1f

// ===========================================================================
// prep: wp1 = [co(48)][40] (k = tap*3+ci, 27..39 = 0)
//       wp2 = [tap(10)][ci8(6)][m(16)][nt(3)][j(8)] halfs, tap 9 = zeros.
// ===========================================================================
__global__ __launch_bounds__(512) void prep_w_k(const float* __restrict__ w1,
                                                const float* __restrict__ w2,
                                                half_t* __restrict__ wp1,
                                                half_t* __restrict__ wp2)
{
    int t = blockIdx.x * 512 + threadIdx.x;
    if (t < 1920) {
        int co = t / 40, kk = t % 40;
        float v = 0.f;
        if (kk < 27) {
            int tap = kk / 3, ci = kk % 3;
            v = w1[((co * 3 + ci) * 3 + tap / 3) * 3 + tap % 3];
        }
        wp1[t] = (half_t)v;
        return;
    }
    int t2 = t - 1920;
    if (t2 >= 23040) return;
    int tap = t2 / 2304, r = t2 % 2304;
    int ci8 = r / 384, r2 = r % 384;
    int mm = r2 / 24, r3 = r2 % 24;
    int nt = r3 / 8, j = r3 % 8;
    int co = nt * 16 + mm, ci = ci8 * 8 + j;
    float v = 0.f;
    if (tap < 9) v = w2[((co * 48 + ci) * 3 + tap / 3) * 3 + tap % 3];
    wp2[t2] = (half_t)v;
}

// ===========================================================================
// Fused conv1(3->48) + conv2(48->48) + bias/leaky + 2x2 maxpool.
// Block: 512 thr = 8 waves; conv2-input tile 16 rows x 32 cols -> pooled 8x16.
// conv1: swapped-operand MFMA -> ds_write_b64 into conv2's A layout.
// conv2: K=(tap,ci) 432 pad 448, 14 steps; B from global L2 with a DEPTH-4
// software pipeline (prologue issued before the barrier).
// Blocks 0..89 also emit wp34 for conv3/conv4.
// ===========================================================================
__global__ __launch_bounds__(512, 4) void conv12_k(const float* __restrict__ x,
                                                   const half_t* __restrict__ wp1,
                                                   const float* __restrict__ b1,
                                                   const half_t* __restrict__ wp2,
                                                   const float* __restrict__ b2,
                                                   const float* __restrict__ w3,
                                                   const float* __restrict__ w4,
                                                   half_t* __restrict__ wp34,
                                                   half_t* __restrict__ out)
{
    __shared__ alignas(16) half_t in_t[624 * 56];   // conv1 out [px=row*34+col][co56]
    __shared__ alignas(16) half_t xt[21][36][4];    // x patch, ci-minor (pad 4)
    __shared__ alignas(16) half_t w1t[1920];        // [co][40]

    const int tid = threadIdx.x;
    const int n = blockIdx.z;
    const int hblk = blockIdx.x * 16, wblk = blockIdx.y * 32;
    const int lane = tid & 63, hp = tid >> 6;       // 8 waves = h-pairs 0..7
    const int m = lane & 15, g = lane >> 4;

    // ---- folded wp3/wp4 prep (blocks 0..89) ----
    {
        int bid = blockIdx.x + 16 * (blockIdx.y + 8 * blockIdx.z);
        int t2 = bid * 512 + tid;
        if (t2 < 46080) {
            int layer = t2 / 23040, r0 = t2 % 23040;
            int tap = r0 / 2304, r = r0 % 2304;
            int ci8 = r / 384, r2 = r % 384;
            int mm = r2 / 24, r3 = r2 % 24;
            int nt = r3 / 8, j = r3 % 8;
            int co = nt * 16 + mm, ci = ci8 * 8 + j;
            const float* src = layer ? w4 : w3;
            float v = 0.f;
            if (tap < 9) v = src[((co * 48 + ci) * 3 + tap / 3) * 3 + tap % 3];
            wp34[t2] = (half_t)v;
        }
    }
    // ---- w1t: linear copy 240 uint4 ----
    {
        const uint4* s = (const uint4*)wp1;
        uint4* d = (uint4*)w1t;
        if (tid < 240) d[tid] = s[tid];
    }
    // ---- xt: rows hblk-2..hblk+18 (21), cols wblk-2..wblk+33 (36) ----
    for (int c = tid; c < 2268; c += 512) {
        int ci = c / 756, rem = c % 756;
        int row = rem / 36, col = rem % 36;
        int gh = hblk - 2 + row, gw = wblk - 2 + col;
        float v = 0.f;
        if ((unsigned)gh < 256u && (unsigned)gw < 256u)
            v = x[((n * 3 + ci) * 256 + gh) * 256 + gw];
        xt[row][col][ci] = (half_t)v;
    }
    __syncthreads();

    // =================== conv1 phase ===================
    int xoff[8];
    #pragma unroll
    for (int j = 0; j < 8; ++j) {
        int k = g * 8 + j;
        int tap = k / 3, ci = k - 3 * tap;
        int dr = tap / 3, ds = tap - 3 * dr;
        xoff[j] = (k < 27) ? ((dr * 36 + ds) * 8 + ci * 2) : 0;   // k>=27: weight=0
    }
    f16x8 wf[3];
    float bb1[12];
    #pragma unroll
    for (int nt = 0; nt < 3; ++nt) {
        wf[nt] = *(const f16x8*)((const char*)w1t + (nt * 16 + m) * 80 + g * 16);
        float4 bv = *(const float4*)(b1 + nt * 16 + 4 * g);
        bb1[nt * 4 + 0] = bv.x; bb1[nt * 4 + 1] = bv.y;
        bb1[nt * 4 + 2] = bv.z; bb1[nt * 4 + 3] = bv.w;
    }
    const char* xtb = (const char*)&xt[0][0][0];
    for (int t = hp; t < 39; t += 8) {
        int px = t * 16 + m;
        int row = px / 34, col = px - row * 34;
        int pxb = (row * 36 + col) * 8;
        f16x8 pf;
        #pragma unroll
        for (int j = 0; j < 8; ++j)
            pf[j] = *(const half_t*)(xtb + pxb + xoff[j]);
        bool inb = ((unsigned)(hblk - 1 + row) < 256u) && ((unsigned)(wblk - 1 + col) < 256u);
        #pragma unroll
        for (int nt = 0; nt < 3; ++nt) {
            f32x4 d = {0.f, 0.f, 0.f, 0.f};
            d = __builtin_amdgcn_mfma_f32_16x16x32_f16(wf[nt], pf, d, 0, 0, 0);
            f16x4 o;
            #pragma unroll
            for (int j = 0; j < 4; ++j) {
                float v = d[j] + bb1[nt * 4 + j];
                v = v > 0.f ? v : LEAKY * v;
                o[j] = inb ? (half_t)v : (half_t)0.f;
            }
            *(f16x4*)(&in_t[px * 56 + nt * 16 + 4 * g]) = o;
        }
    }

    // =================== conv2 phase (depth-4 B pipeline) ===================
    const int hpar = m & 1, wloc = m >> 1;
    const int abase = hp * 7616;                    // 2*hp * 34 * 112
    const char* ib = (const char*)in_t;
    const char* bp = (const char*)wp2 + m * 48;

    f16x8 bf[4][3], af[4];

#define BLOAD(S) { \
    int kc = 4 * (S) + g; int tap = kc / 6, ci8 = kc - tap * 6; \
    int boff = tap * 4608 + ci8 * 768; \
    bf[(S) & 3][0] = *(const f16x8*)(bp + boff); \
    bf[(S) & 3][1] = *(const f16x8*)(bp + boff + 16); \
    bf[(S) & 3][2] = *(const f16x8*)(bp + boff + 32); }
#define ALOAD(S) { \
    int kc = 4 * (S) + g; int tap = kc / 6, ci8 = kc - tap * 6; \
    int dr = tap / 3, ds = tap - 3 * dr; \
    if (tap == 9) { dr = 0; ds = 0; } \
    int aoff = ((hpar + dr) * 34 + (wloc + ds)) * 112 + ci8 * 16 + abase; \
    af[0] = *(const f16x8*)(ib + aoff); \
    af[1] = *(const f16x8*)(ib + aoff + 896); \
    af[2] = *(const f16x8*)(ib + aoff + 1792); \
    af[3] = *(const f16x8*)(ib + aoff + 2688); }
#define MM(P) { \
    __builtin_amdgcn_s_setprio(1); \
    _Pragma("unroll") \
    for (int mt = 0; mt < 4; ++mt) { \
        acc[mt][0] = __builtin_amdgcn_mfma_f32_16x16x32_f16(af[mt], bf[P][0], acc[mt][0], 0, 0, 0); \
        acc[mt][1] = __builtin_amdgcn_mfma_f32_16x16x32_f16(af[mt], bf[P][1], acc[mt][1], 0, 0, 0); \
        acc[mt][2] = __builtin_amdgcn_mfma_f32_16x16x32_f16(af[mt], bf[P][2], acc[mt][2], 0, 0, 0); \
    } \
    __builtin_amdgcn_s_setprio(0); }

    // prologue: B for steps 0..3 in flight across the barrier
    BLOAD(0); BLOAD(1); BLOAD(2); BLOAD(3);
    __syncthreads();

    f32x4 acc[4][3];
    #pragma unroll
    for (int mt = 0; mt < 4; ++mt)
        #pragma unroll
        for (int nt = 0; nt < 3; ++nt)
            acc[mt][nt] = (f32x4){0.f, 0.f, 0.f, 0.f};

    #pragma unroll
    for (int s = 0; s < 14; ++s) {
        ALOAD(s);
        MM(s & 3);
        if (s < 10) BLOAD(s + 4);
    }
#undef BLOAD
#undef ALOAD
#undef MM

    // ---- epilogue: bias + leaky + 2x2 maxpool -> act2 NHWC-48 ----
    int hq = blockIdx.x * 8 + hp;
    #pragma unroll
    for (int nt = 0; nt < 3; ++nt) {
        int co = nt * 16 + m;
        float bb = b2[co];
        #pragma unroll
        for (int mt = 0; mt < 4; ++mt) {
            float pmax = -1e30f;
            #pragma unroll
            for (int j = 0; j < 4; ++j) {
                float v = acc[mt][nt][j] + bb;
                v = v > 0.f ? v : LEAKY * v;
                pmax = fmaxf(pmax, v);
            }
            int wq = blockIdx.y * 16 + mt * 4 + g;
            out[((n * 128 + hq) * 128 + wq) * 48 + co] = (half_t)pmax;
        }
    }
}

// ===========================================================================
// convpool (48->48, 3x3 pad1 + bias + leaky + 2x2 maxpool), depth-4 B pipe.
// Block: 256 thr = 4 waves; wave = 1 h-pair x (8*MT) cols. A: LDS; B: global.
// NTS = couts/16 per block; grid z = ntb*8 + n.
// ===========================================================================
template<int H, int W, int MT, int NTS, bool FINAL>
__global__ __launch_bounds__(256, 4)
void convpool4_k(const half_t* __restrict__ in,
                 const half_t* __restrict__ wp,
                 const float* __restrict__ bias,
                 void* __restrict__ outv)
{
    constexpr int HO = H / 2, WO = W / 2;
    constexpr int TC = 8 * MT + 2;
    constexpr int NU4 = 10 * TC * 6;

    __shared__ alignas(16) half_t in_t[10][TC][56];

    int tid = threadIdx.x;
    int n = blockIdx.z & 7, ntb = blockIdx.z >> 3;
    int hblk = blockIdx.x * 8, wblk = blockIdx.y * (8 * MT);
    int lane = tid & 63, hp = tid >> 6;
    int m = lane & 15, g = lane >> 4;
    int hpar = m & 1, wloc = m >> 1;

    {
        const uint4* s4 = (const uint4*)in;
        uint4* d = (uint4*)&in_t[0][0][0];
        #pragma unroll
        for (int i = 0; i < (NU4 + 255) / 256; ++i) {
            int c = tid + i * 256;
            if (c < NU4) {
                int row = c / (TC * 6);
                int rem = c - row * (TC * 6);
                int pix = rem / 6;
                int sub = rem - pix * 6;
                int gh = hblk - 1 + row, gw = wblk - 1 + pix;
                uint4 v = {0u, 0u, 0u, 0u};
                if ((unsigned)gh < (unsigned)H && (unsigned)gw < (unsigned)W)
                    v = s4[((n * H + gh) * W + gw) * 6 + sub];
                d[(row * TC + pix) * 7 + sub] = v;
            }
        }
    }

    int abase = hp * 2 * TC * 112;
    const char* ib = (const char*)&in_t[0][0][0];
    const char* bp = (const char*)wp + m * 48 + ntb * NTS * 16;

    f16x8 bf[4][NTS], a[MT];

#define BLOAD(S) { \
    int kc = 4 * (S) + g; int tap = kc / 6, ci8 = kc - tap * 6; \
    int boff = tap * 4608 + ci8 * 768; \
    _Pragma("unroll") \
    for (int nt = 0; nt < NTS; ++nt) \
        bf[(S) & 3][nt] = *(const f16x8*)(bp + boff + nt * 16); }

    BLOAD(0); BLOAD(1); BLOAD(2); BLOAD(3);

    f32x4 acc[MT][NTS];
    #pragma unroll
    for (int mt = 0; mt < MT; ++mt)
        #pragma unroll
        for (int nt = 0; nt < NTS; ++nt)
            acc[mt][nt] = (f32x4){0.f, 0.f, 0.f, 0.f};

    __syncthreads();

    #pragma unroll
    for (int s = 0; s < 14; ++s) {
        int kc = 4 * s + g;
        int tap = kc / 6, ci8 = kc - tap * 6;
        int dr = tap / 3, ds = tap - 3 * dr;
        if (tap == 9) { dr = 0; ds = 0; }
        int aoff = ((hpar + dr) * TC + (wloc + ds)) * 112 + ci8 * 16;
        #pragma unroll
        for (int mt = 0; mt < MT; ++mt)
            a[mt] = *(const f16x8*)(ib + abase + aoff + mt * 896);
        __builtin_amdgcn_s_setprio(1);
        #pragma unroll
        for (int mt = 0; mt < MT; ++mt)
            #pragma unroll
            for (int nt = 0; nt < NTS; ++nt)
                acc[mt][nt] = __builtin_amdgcn_mfma_f32_16x16x32_f16(a[mt], bf[s & 3][nt], acc[mt][nt], 0, 0, 0);
        __builtin_amdgcn_s_setprio(0);
        if (s < 10) BLOAD(s + 4);
    }
#undef BLOAD

    int hq = blockIdx.x * 4 + hp;
    #pragma unroll
    for (int nt = 0; nt < NTS; ++nt) {
        int co = (ntb * NTS + nt) * 16 + m;
        float bb = bias[co];
        #pragma unroll
        for (int mt = 0; mt < MT; ++mt) {
            float pmax = -1e30f;
            #pragma unroll
            for (int j = 0; j < 4; ++j) {
                float v = acc[mt][nt][j] + bb;
                v = v > 0.f ? v : LEAKY * v;
                pmax = fmaxf(pmax, v);
            }
            int wq = blockIdx.y * (4 * MT) + mt * 4 + g;
            if (FINAL)
                ((float*)outv)[(((long)n * 48 + co) * HO + hq) * WO + wq] = pmax;
            else
                ((half_t*)outv)[((n * HO + hq) * WO + wq) * 48 + co] = (half_t)pmax;
        }
    }
}

// ===========================================================================
extern "C" void kernel_launch(void* const* d_in, const int* in_sizes, int n_in,
                              void* d_out, int out_size, void* d_ws, size_t ws_size,
                              hipStream_t stream)
{
    const float* x  = (const float*)d_in[0];
    const float* w1 = (const float*)d_in[1];
    const float* b1 = (const float*)d_in[2];
    const float* w2 = (const float*)d_in[3];
    const float* b2 = (const float*)d_in[4];
    const float* w3 = (const float*)d_in[5];
    const float* b3 = (const float*)d_in[6];
    const float* w4 = (const float*)d_in[7];
    const float* b4 = (const float*)d_in[8];

    half_t* Wb = (half_t*)d_ws;
    half_t* wp1  = Wb;                      // 1920 (pad 2048)
    half_t* wp2  = Wb + 2048;               // 23040
    half_t* wp34 = wp2 + 23040;             // 2 x 23040
    half_t* act2 = wp34 + 46080;            // 8*128*128*48 = 6291456
    half_t* act3 = act2 + 6291456;          // 8*64*64*48   = 1572864

    prep_w_k<<<dim3(49), 512, 0, stream>>>(w1, w2, wp1, wp2);

    // fused conv1+conv2: 3->48->48 @256 + pool -> act2 (128x128 NHWC-48)
    conv12_k<<<dim3(16, 8, 8), 512, 0, stream>>>(x, wp1, b1, wp2, b2, w3, w4, wp34, act2);
    // conv3: 48->48 @128 + pool -> 64
    convpool4_k<128, 128, 4, 3, false><<<dim3(16, 4, 8), 256, 0, stream>>>(act2, wp34, b3, act3);
    // conv4: 48->48 @64 + pool -> 32, fp32 NCHW out; cout split 3-ways
    convpool4_k<64, 64, 2, 1, true><<<dim3(8, 4, 24), 256, 0, stream>>>(act3, wp34 + 23040, b4, d_out);
}